// Round 4
// baseline (135.641 us; speedup 1.0000x reference)
//
#include <hip/hip_runtime.h>
#include <hip/hip_cooperative_groups.h>
#include <math.h>

namespace cg = cooperative_groups;

#define NBLK 256
#define NTHR 256
#define K_FINE 2048
#define HW 147456          // 384*384
#define N1 1179648         // 8*HW
#define IMG 384
#define NHC 24             // hist chunks per batch
#define NHIST 192          // 8*24
#define NTILE 1152         // 8 * 144 ssim tiles

// ws word offsets (total ~19.5k words = 78 KB)
#define WS_PMM   0                      // 3 tensors * 256 blocks * {min,max}
#define WS_HIST  1536                   // 8*2048 ints (global atomic hist)
#define WS_DEPTH 17920                  // 192 floats
#define WS_SSIM  18112                  // 1152 floats
#define WS_UNIF  19264                  // 256 floats

#define SMEMF (42*43*2 + 42*33*5)       // 10542 floats = 42.2 KB (union buffer)

__global__ __launch_bounds__(NTHR) void k_mega(
        const float* __restrict__ x, const float* __restrict__ tg,
        const float* __restrict__ dp, float* __restrict__ wsf,
        float* __restrict__ out)
{
    cg::grid_group grid = cg::this_grid();
    __shared__ float smem[SMEMF];
    __shared__ float swred[4][8];
    __shared__ float s8[8];
    const int tid = threadIdx.x;
    const int bid = blockIdx.x;

    // ---------------- P1: per-block min/max partials + zero hist -----------
    {
        const float4* x4 = (const float4*)x  + bid * 1152;
        const float4* t4 = (const float4*)tg + bid * 1152;
        const float4* d4 = (const float4*)dp + bid * 1152;
        float mn0 = 3.4e38f, mx0 = -3.4e38f;
        float mn1 = 3.4e38f, mx1 = -3.4e38f;
        float mn2 = 3.4e38f, mx2 = -3.4e38f;
        for (int i = tid; i < 1152; i += NTHR) {
            float4 v = x4[i];
            mn0 = fminf(mn0, fminf(fminf(v.x, v.y), fminf(v.z, v.w)));
            mx0 = fmaxf(mx0, fmaxf(fmaxf(v.x, v.y), fmaxf(v.z, v.w)));
            v = t4[i];
            mn1 = fminf(mn1, fminf(fminf(v.x, v.y), fminf(v.z, v.w)));
            mx1 = fmaxf(mx1, fmaxf(fmaxf(v.x, v.y), fmaxf(v.z, v.w)));
            v = d4[i];
            mn2 = fminf(mn2, fminf(fminf(v.x, v.y), fminf(v.z, v.w)));
            mx2 = fmaxf(mx2, fmaxf(fmaxf(v.x, v.y), fmaxf(v.z, v.w)));
        }
        #pragma unroll
        for (int off = 32; off; off >>= 1) {
            mn0 = fminf(mn0, __shfl_down(mn0, off, 64));
            mx0 = fmaxf(mx0, __shfl_down(mx0, off, 64));
            mn1 = fminf(mn1, __shfl_down(mn1, off, 64));
            mx1 = fmaxf(mx1, __shfl_down(mx1, off, 64));
            mn2 = fminf(mn2, __shfl_down(mn2, off, 64));
            mx2 = fmaxf(mx2, __shfl_down(mx2, off, 64));
        }
        if ((tid & 63) == 0) {
            int w = tid >> 6;
            swred[w][0] = mn0; swred[w][1] = mx0; swred[w][2] = mn1;
            swred[w][3] = mx1; swred[w][4] = mn2; swred[w][5] = mx2;
        }
        __syncthreads();
        if (tid == 0) {
            #pragma unroll
            for (int w = 1; w < 4; w++) {
                swred[0][0] = fminf(swred[0][0], swred[w][0]);
                swred[0][1] = fmaxf(swred[0][1], swred[w][1]);
                swred[0][2] = fminf(swred[0][2], swred[w][2]);
                swred[0][3] = fmaxf(swred[0][3], swred[w][3]);
                swred[0][4] = fminf(swred[0][4], swred[w][4]);
                swred[0][5] = fmaxf(swred[0][5], swred[w][5]);
            }
            wsf[WS_PMM +        bid * 2]     = swred[0][0];
            wsf[WS_PMM +        bid * 2 + 1] = swred[0][1];
            wsf[WS_PMM + 512  + bid * 2]     = swred[0][2];
            wsf[WS_PMM + 512  + bid * 2 + 1] = swred[0][3];
            wsf[WS_PMM + 1024 + bid * 2]     = swred[0][4];
            wsf[WS_PMM + 1024 + bid * 2 + 1] = swred[0][5];
        }
        if (tid < 64) ((int*)wsf)[WS_HIST + bid * 64 + tid] = 0;
    }
    grid.sync();

    // ---------------- P2a: redundant global min/max reduce -----------------
    float xmn, xinv, tmn, tinv, dmn, dinv;
    {
        const float2* pm = (const float2*)&wsf[WS_PMM];
        float2 a = pm[tid], b = pm[256 + tid], c = pm[512 + tid];
        float mn0 = a.x, mx0 = a.y, mn1 = b.x, mx1 = b.y, mn2 = c.x, mx2 = c.y;
        #pragma unroll
        for (int off = 32; off; off >>= 1) {
            mn0 = fminf(mn0, __shfl_down(mn0, off, 64));
            mx0 = fmaxf(mx0, __shfl_down(mx0, off, 64));
            mn1 = fminf(mn1, __shfl_down(mn1, off, 64));
            mx1 = fmaxf(mx1, __shfl_down(mx1, off, 64));
            mn2 = fminf(mn2, __shfl_down(mn2, off, 64));
            mx2 = fmaxf(mx2, __shfl_down(mx2, off, 64));
        }
        __syncthreads();
        if ((tid & 63) == 0) {
            int w = tid >> 6;
            swred[w][0] = mn0; swred[w][1] = mx0; swred[w][2] = mn1;
            swred[w][3] = mx1; swred[w][4] = mn2; swred[w][5] = mx2;
        }
        __syncthreads();
        mn0 = fminf(fminf(swred[0][0], swred[1][0]), fminf(swred[2][0], swred[3][0]));
        mx0 = fmaxf(fmaxf(swred[0][1], swred[1][1]), fmaxf(swred[2][1], swred[3][1]));
        mn1 = fminf(fminf(swred[0][2], swred[1][2]), fminf(swred[2][2], swred[3][2]));
        mx1 = fmaxf(fmaxf(swred[0][3], swred[1][3]), fmaxf(swred[2][3], swred[3][3]));
        mn2 = fminf(fminf(swred[0][4], swred[1][4]), fminf(swred[2][4], swred[3][4]));
        mx2 = fmaxf(fmaxf(swred[0][5], swred[1][5]), fmaxf(swred[2][5], swred[3][5]));
        xmn = mn0; xinv = 1.0f / (mx0 - mn0);
        tmn = mn1; tinv = 1.0f / (mx1 - mn1);
        dmn = mn2; dinv = 1.0f / (mx2 - mn2);
        __syncthreads();
    }

    // gaussian window (11 taps, sigma=1.5, normalized)
    float g[11];
    {
        float s = 0.f;
        #pragma unroll
        for (int i = 0; i < 11; i++) {
            float dd = (float)(i - 5);
            g[i] = expf(-dd * dd / 4.5f);
            s += g[i];
        }
        float is = 1.0f / s;
        #pragma unroll
        for (int i = 0; i < 11; i++) g[i] *= is;
    }

    // ---------------- P2b: 1152 ssim tiles + 192 hist/depth chunks ---------
    for (int item = bid; item < NTILE + NHIST; item += NBLK) {
        if (item < NTILE) {
            float* sO = smem;                  // [42][43]
            float* sI = smem + 42 * 43;
            float* hr = smem + 2 * 42 * 43;    // 5 x [42][33]
            const int HRS = 42 * 33;
            int img = item / 144;
            int tl  = item % 144;
            int ty0 = (tl / 12) * 32 - 5;
            int tx0 = (tl % 12) * 32 - 5;
            const float* xb = x  + (size_t)img * HW;
            const float* tb = tg + (size_t)img * HW;
            for (int idx = tid; idx < 42 * 42; idx += NTHR) {
                int rr = idx / 42, cc = idx % 42;
                int gy = ty0 + rr, gx = tx0 + cc;
                float xv = 0.f, tv = 0.f;
                if (gy >= 0 && gy < IMG && gx >= 0 && gx < IMG) {
                    int o = gy * IMG + gx;
                    xv = (xb[o] - xmn) * xinv;
                    tv = (tb[o] - tmn) * tinv;
                }
                sO[rr * 43 + cc] = xv; sI[rr * 43 + cc] = tv;
            }
            __syncthreads();
            for (int idx = tid; idx < 42 * 32; idx += NTHR) {
                int rr = idx >> 5, cx = idx & 31;
                float so = 0, si = 0, soo = 0, sii = 0, soi = 0;
                #pragma unroll
                for (int dx2 = 0; dx2 < 11; dx2++) {
                    float o  = sO[rr * 43 + cx + dx2];
                    float ii = sI[rr * 43 + cx + dx2];
                    float w  = g[dx2];
                    so += w * o; si += w * ii;
                    soo += w * o * o; sii += w * ii * ii; soi += w * o * ii;
                }
                int hb = rr * 33 + cx;
                hr[hb] = so; hr[HRS + hb] = si; hr[2 * HRS + hb] = soo;
                hr[3 * HRS + hb] = sii; hr[4 * HRS + hb] = soi;
            }
            __syncthreads();
            const float C1 = 1e-4f, C2 = 9e-4f;
            float lsum = 0.f;
            for (int idx = tid; idx < 1024; idx += NTHR) {
                int oy = idx >> 5, ox = idx & 31;
                float mu1 = 0, mu2 = 0, m11 = 0, m22 = 0, m12 = 0;
                #pragma unroll
                for (int dy = 0; dy < 11; dy++) {
                    float w = g[dy];
                    int hb = (oy + dy) * 33 + ox;
                    mu1 += w * hr[hb]; mu2 += w * hr[HRS + hb];
                    m11 += w * hr[2 * HRS + hb]; m22 += w * hr[3 * HRS + hb];
                    m12 += w * hr[4 * HRS + hb];
                }
                float mu1s = mu1 * mu1, mu2s = mu2 * mu2, mu12 = mu1 * mu2;
                float s1 = m11 - mu1s, s2 = m22 - mu2s, s12 = m12 - mu12;
                lsum += ((2.f * mu12 + C1) * (2.f * s12 + C2))
                      / ((mu1s + mu2s + C1) * (s1 + s2 + C2));
            }
            #pragma unroll
            for (int off = 32; off; off >>= 1) lsum += __shfl_down(lsum, off, 64);
            if ((tid & 63) == 0) swred[tid >> 6][6] = lsum;
            __syncthreads();
            if (tid == 0)
                wsf[WS_SSIM + item] = swred[0][6] + swred[1][6] + swred[2][6] + swred[3][6];
            __syncthreads();
        } else {
            int c = item - NTILE;
            int* lh = (int*)smem;
            for (int i = tid; i < K_FINE; i += NTHR) lh[i] = 0;
            __syncthreads();
            int batch = c / NHC, chunk = c % NHC;
            const float4* x4 = (const float4*)x  + (size_t)batch * (HW / 4) + chunk * 1536;
            const float4* d4 = (const float4*)dp + (size_t)batch * (HW / 4) + chunk * 1536;
            float dsum = 0.f;
            for (int i = tid; i < 1536; i += NTHR) {
                float4 xv = x4[i], dv = d4[i];
                float o0 = (xv.x - xmn) * xinv, o1 = (xv.y - xmn) * xinv;
                float o2 = (xv.z - xmn) * xinv, o3 = (xv.w - xmn) * xinv;
                dsum += o0 * ((dv.x - dmn) * dinv) + o1 * ((dv.y - dmn) * dinv)
                      + o2 * ((dv.z - dmn) * dinv) + o3 * ((dv.w - dmn) * dinv);
                int j0 = min(K_FINE - 1, max(0, (int)(o0 * K_FINE)));
                int j1 = min(K_FINE - 1, max(0, (int)(o1 * K_FINE)));
                int j2 = min(K_FINE - 1, max(0, (int)(o2 * K_FINE)));
                int j3 = min(K_FINE - 1, max(0, (int)(o3 * K_FINE)));
                atomicAdd(lh + j0, 1); atomicAdd(lh + j1, 1);
                atomicAdd(lh + j2, 1); atomicAdd(lh + j3, 1);
            }
            __syncthreads();
            int* gh = (int*)wsf + WS_HIST + batch * K_FINE;
            for (int i = tid; i < K_FINE; i += NTHR) {
                int v = lh[i];
                if (v) atomicAdd(gh + i, v);
            }
            #pragma unroll
            for (int off = 32; off; off >>= 1) dsum += __shfl_down(dsum, off, 64);
            if ((tid & 63) == 0) swred[tid >> 6][6] = dsum;
            __syncthreads();
            if (tid == 0)
                wsf[WS_DEPTH + c] = swred[0][6] + swred[1][6] + swred[2][6] + swred[3][6];
            __syncthreads();
        }
    }
    grid.sync();

    // ---------------- P3: soft-hist entropy (all 256 blocks) ---------------
    {
        int* lh = (int*)smem;
        int batch = bid >> 5;
        const int* gh = (const int*)wsf + WS_HIST + batch * K_FINE;
        for (int i = tid; i < K_FINE; i += NTHR) lh[i] = gh[i];
        __syncthreads();
        int binLocal = tid >> 5, slice = tid & 31;
        int bin = (bid & 31) * 8 + binLocal;
        const float delta = 1.0f / 256.0f;
        const float r   = expf(3.0f * delta);
        const float rm1 = r - 1.0f;
        const float c32 = expf(-3.0f * 32.0f / (float)K_FINE);
        float L = (float)bin * delta;
        float u = expf(3.0f * (L - ((float)slice + 0.5f) * (1.0f / (float)K_FINE)));
        float h = 0.f;
        #pragma unroll 4
        for (int j = slice; j < K_FINE; j += 32) {
            float cnt = (float)lh[j];
            float t1 = 1.0f + u;
            float t2 = fmaf(u, r, 1.0f);
            h = fmaf(cnt * (u * rm1), __builtin_amdgcn_rcpf(t1 * t2), h);
            u *= c32;
        }
        #pragma unroll
        for (int off = 16; off; off >>= 1) h += __shfl_down(h, off, 32);
        if (slice == 0) s8[binLocal] = h;
        __syncthreads();
        if (tid == 0) {
            float hl = 0.f;
            #pragma unroll
            for (int b = 0; b < 8; b++) {
                float hh = s8[b];
                hl += (hh > 0.f) ? hh * logf(hh) : 0.f;
            }
            wsf[WS_UNIF + bid] = hl;
        }
    }
    grid.sync();

    // ---------------- P4: final deterministic combine (block 0) ------------
    if (bid == 0) {
        float a = 0.f, bsum = 0.f, c = 0.f;
        for (int i = tid; i < NHIST; i += NTHR) a    += wsf[WS_DEPTH + i];
        for (int i = tid; i < NTILE; i += NTHR) bsum += wsf[WS_SSIM + i];
        for (int i = tid; i < 256;   i += NTHR) c    += wsf[WS_UNIF + i];
        float* ra = smem; float* rb = smem + 256; float* rc = smem + 512;
        ra[tid] = a; rb[tid] = bsum; rc[tid] = c;
        __syncthreads();
        for (int s = 128; s; s >>= 1) {
            if (tid < s) {
                ra[tid] += ra[tid + s];
                rb[tid] += rb[tid + s];
                rc[tid] += rc[tid + s];
            }
            __syncthreads();
        }
        if (tid == 0) {
            float uniform  = rc[0] / 8.0f;
            float depthL   = ra[0] / 8.0f;
            float ssimMean = rb[0] / (float)N1;
            out[0] = 1e-6f * uniform + 1e-5f * depthL + (1.0f - ssimMean);
        }
    }
}

extern "C" void kernel_launch(void* const* d_in, const int* in_sizes, int n_in,
                              void* d_out, int out_size, void* d_ws, size_t ws_size,
                              hipStream_t stream) {
    const float* x  = (const float*)d_in[0];
    const float* tg = (const float*)d_in[1];
    const float* dp = (const float*)d_in[2];
    float* wsf = (float*)d_ws;
    float* out = (float*)d_out;
    void* args[] = { (void*)&x, (void*)&tg, (void*)&dp, (void*)&wsf, (void*)&out };
    hipLaunchCooperativeKernel((const void*)k_mega, dim3(NBLK), dim3(NTHR),
                               args, 0, stream);
}

// Round 5
// 40.617 us; speedup vs baseline: 3.3395x; 3.3395x over previous
//
#include <hip/hip_runtime.h>
#include <math.h>

#define NTHR 256
#define K_FINE 2048
#define HW 147456          // 384*384
#define N1 1179648         // 8*HW
#define IMG 384
#define NHC 24             // hist chunks per batch
#define NHIST 192          // 8*24
#define NTILE 1152         // 8 * 144 ssim tiles

// ws word offsets
#define WS_PMM    0                     // [3][256][2] floats
#define WS_HIST   1536                  // 8*2048 ints
#define WS_DEPTH  17920                 // 192 floats
#define WS_SSIM   18112                 // 1152 floats
#define WS_UNIF   19264                 // 256 floats
#define WS_TICKET 19520                 // 1 int

#define HRS (42*33)
#define SMEMF (42*43*2 + 3*HRS)         // 7770 floats = 31.1 KB

// ================= K1: per-block min/max partials; zero hist/ticket =========
__global__ __launch_bounds__(NTHR) void k_minmax(
        const float* __restrict__ x, const float* __restrict__ tg,
        const float* __restrict__ dp, float* __restrict__ wsf)
{
    __shared__ float swred[4][8];
    const int tid = threadIdx.x, bid = blockIdx.x;
    const float4* x4 = (const float4*)x  + bid * 1152;
    const float4* t4 = (const float4*)tg + bid * 1152;
    const float4* d4 = (const float4*)dp + bid * 1152;
    float mn0 = 3.4e38f, mx0 = -3.4e38f;
    float mn1 = 3.4e38f, mx1 = -3.4e38f;
    float mn2 = 3.4e38f, mx2 = -3.4e38f;
    for (int i = tid; i < 1152; i += NTHR) {
        float4 v = x4[i];
        mn0 = fminf(mn0, fminf(fminf(v.x, v.y), fminf(v.z, v.w)));
        mx0 = fmaxf(mx0, fmaxf(fmaxf(v.x, v.y), fmaxf(v.z, v.w)));
        v = t4[i];
        mn1 = fminf(mn1, fminf(fminf(v.x, v.y), fminf(v.z, v.w)));
        mx1 = fmaxf(mx1, fmaxf(fmaxf(v.x, v.y), fmaxf(v.z, v.w)));
        v = d4[i];
        mn2 = fminf(mn2, fminf(fminf(v.x, v.y), fminf(v.z, v.w)));
        mx2 = fmaxf(mx2, fmaxf(fmaxf(v.x, v.y), fmaxf(v.z, v.w)));
    }
    #pragma unroll
    for (int off = 32; off; off >>= 1) {
        mn0 = fminf(mn0, __shfl_down(mn0, off, 64));
        mx0 = fmaxf(mx0, __shfl_down(mx0, off, 64));
        mn1 = fminf(mn1, __shfl_down(mn1, off, 64));
        mx1 = fmaxf(mx1, __shfl_down(mx1, off, 64));
        mn2 = fminf(mn2, __shfl_down(mn2, off, 64));
        mx2 = fmaxf(mx2, __shfl_down(mx2, off, 64));
    }
    if ((tid & 63) == 0) {
        int w = tid >> 6;
        swred[w][0] = mn0; swred[w][1] = mx0; swred[w][2] = mn1;
        swred[w][3] = mx1; swred[w][4] = mn2; swred[w][5] = mx2;
    }
    __syncthreads();
    if (tid == 0) {
        #pragma unroll
        for (int w = 1; w < 4; w++) {
            swred[0][0] = fminf(swred[0][0], swred[w][0]);
            swred[0][1] = fmaxf(swred[0][1], swred[w][1]);
            swred[0][2] = fminf(swred[0][2], swred[w][2]);
            swred[0][3] = fmaxf(swred[0][3], swred[w][3]);
            swred[0][4] = fminf(swred[0][4], swred[w][4]);
            swred[0][5] = fmaxf(swred[0][5], swred[w][5]);
        }
        wsf[WS_PMM +        bid * 2]     = swred[0][0];
        wsf[WS_PMM +        bid * 2 + 1] = swred[0][1];
        wsf[WS_PMM + 512  + bid * 2]     = swred[0][2];
        wsf[WS_PMM + 512  + bid * 2 + 1] = swred[0][3];
        wsf[WS_PMM + 1024 + bid * 2]     = swred[0][4];
        wsf[WS_PMM + 1024 + bid * 2 + 1] = swred[0][5];
        if (bid == 0) ((int*)wsf)[WS_TICKET] = 0;
    }
    if (tid < 64) ((int*)wsf)[WS_HIST + bid * 64 + tid] = 0;
}

// helper: per-block redundant global min/max reduce from partials
__device__ __forceinline__ void reduce_minmax(
        const float* __restrict__ wsf, float swred[4][8], int tid,
        float& xmn, float& xinv, float& tmn, float& tinv, float& dmn, float& dinv)
{
    const float2* pm = (const float2*)&wsf[WS_PMM];
    float2 a = pm[tid], b = pm[256 + tid], c = pm[512 + tid];
    float mn0 = a.x, mx0 = a.y, mn1 = b.x, mx1 = b.y, mn2 = c.x, mx2 = c.y;
    #pragma unroll
    for (int off = 32; off; off >>= 1) {
        mn0 = fminf(mn0, __shfl_down(mn0, off, 64));
        mx0 = fmaxf(mx0, __shfl_down(mx0, off, 64));
        mn1 = fminf(mn1, __shfl_down(mn1, off, 64));
        mx1 = fmaxf(mx1, __shfl_down(mx1, off, 64));
        mn2 = fminf(mn2, __shfl_down(mn2, off, 64));
        mx2 = fmaxf(mx2, __shfl_down(mx2, off, 64));
    }
    if ((tid & 63) == 0) {
        int w = tid >> 6;
        swred[w][0] = mn0; swred[w][1] = mx0; swred[w][2] = mn1;
        swred[w][3] = mx1; swred[w][4] = mn2; swred[w][5] = mx2;
    }
    __syncthreads();
    mn0 = fminf(fminf(swred[0][0], swred[1][0]), fminf(swred[2][0], swred[3][0]));
    mx0 = fmaxf(fmaxf(swred[0][1], swred[1][1]), fmaxf(swred[2][1], swred[3][1]));
    mn1 = fminf(fminf(swred[0][2], swred[1][2]), fminf(swred[2][2], swred[3][2]));
    mx1 = fmaxf(fmaxf(swred[0][3], swred[1][3]), fmaxf(swred[2][3], swred[3][3]));
    mn2 = fminf(fminf(swred[0][4], swred[1][4]), fminf(swred[2][4], swred[3][4]));
    mx2 = fmaxf(fmaxf(swred[0][5], swred[1][5]), fmaxf(swred[2][5], swred[3][5]));
    xmn = mn0; xinv = 1.0f / (mx0 - mn0);
    tmn = mn1; tinv = 1.0f / (mx1 - mn1);
    dmn = mn2; dinv = 1.0f / (mx2 - mn2);
    __syncthreads();
}

// ================= K2: fused SSIM tiles + hist/depth chunks =================
__global__ __launch_bounds__(NTHR) void k_work(
        const float* __restrict__ x, const float* __restrict__ tg,
        const float* __restrict__ dp, float* __restrict__ wsf)
{
    __shared__ float smem[SMEMF];
    __shared__ float swred[4][8];
    const int tid = threadIdx.x, bid = blockIdx.x;

    float xmn, xinv, tmn, tinv, dmn, dinv;
    reduce_minmax(wsf, swred, tid, xmn, xinv, tmn, tinv, dmn, dinv);

    if (bid < NTILE) {
        // -------- SSIM tile (32x32 out, 42x42 halo, two-pass moments) ------
        float g[11];
        {
            float s = 0.f;
            #pragma unroll
            for (int i = 0; i < 11; i++) {
                float dd = (float)(i - 5);
                g[i] = expf(-dd * dd / 4.5f);
                s += g[i];
            }
            float is = 1.0f / s;
            #pragma unroll
            for (int i = 0; i < 11; i++) g[i] *= is;
        }
        float* sO  = smem;                 // [42][43]
        float* sI  = smem + 42 * 43;
        float* hr0 = smem + 2 * 42 * 43;   // [42][33] x3
        float* hr1 = hr0 + HRS;
        float* hr2 = hr1 + HRS;
        int img = bid / 144;
        int tl  = bid % 144;
        int ty0 = (tl / 12) * 32 - 5;
        int tx0 = (tl % 12) * 32 - 5;
        const float* xb = x  + (size_t)img * HW;
        const float* tb = tg + (size_t)img * HW;
        for (int idx = tid; idx < 42 * 42; idx += NTHR) {
            int rr = idx / 42, cc = idx % 42;
            int gy = ty0 + rr, gx = tx0 + cc;
            float xv = 0.f, tv = 0.f;
            if (gy >= 0 && gy < IMG && gx >= 0 && gx < IMG) {
                int o = gy * IMG + gx;
                xv = (xb[o] - xmn) * xinv;
                tv = (tb[o] - tmn) * tinv;
            }
            sO[rr * 43 + cc] = xv; sI[rr * 43 + cc] = tv;
        }
        __syncthreads();
        // pass A horiz: mu channels
        for (int idx = tid; idx < 42 * 32; idx += NTHR) {
            int rr = idx >> 5, cx = idx & 31;
            const float* rowO = sO + rr * 43 + cx;
            const float* rowI = sI + rr * 43 + cx;
            float so = 0, si = 0;
            #pragma unroll
            for (int d = 0; d < 11; d++) { so += g[d] * rowO[d]; si += g[d] * rowI[d]; }
            hr0[rr * 33 + cx] = so; hr1[rr * 33 + cx] = si;
        }
        __syncthreads();
        // pass A vert: mu1/mu2 into registers (4-row strip per thread)
        const int ox = tid & 31, oy0 = (tid >> 5) << 2;
        float mu1[4], mu2[4];
        {
            float w0[14], w1[14];
            #pragma unroll
            for (int k = 0; k < 14; k++) {
                int hb = (oy0 + k) * 33 + ox;
                w0[k] = hr0[hb]; w1[k] = hr1[hb];
            }
            #pragma unroll
            for (int p = 0; p < 4; p++) {
                float m1 = 0, m2 = 0;
                #pragma unroll
                for (int dy = 0; dy < 11; dy++) {
                    m1 += g[dy] * w0[p + dy];
                    m2 += g[dy] * w1[p + dy];
                }
                mu1[p] = m1; mu2[p] = m2;
            }
        }
        __syncthreads();
        // pass B horiz: second moments
        for (int idx = tid; idx < 42 * 32; idx += NTHR) {
            int rr = idx >> 5, cx = idx & 31;
            const float* rowO = sO + rr * 43 + cx;
            const float* rowI = sI + rr * 43 + cx;
            float soo = 0, sii = 0, soi = 0;
            #pragma unroll
            for (int d = 0; d < 11; d++) {
                float o = rowO[d], ii = rowI[d], w = g[d];
                soo += w * o * o; sii += w * ii * ii; soi += w * o * ii;
            }
            int hb = rr * 33 + cx;
            hr0[hb] = soo; hr1[hb] = sii; hr2[hb] = soi;
        }
        __syncthreads();
        // pass B vert + formula
        const float C1 = 1e-4f, C2 = 9e-4f;
        float lsum = 0.f;
        {
            float w0[14], w1[14], w2[14];
            #pragma unroll
            for (int k = 0; k < 14; k++) {
                int hb = (oy0 + k) * 33 + ox;
                w0[k] = hr0[hb]; w1[k] = hr1[hb]; w2[k] = hr2[hb];
            }
            #pragma unroll
            for (int p = 0; p < 4; p++) {
                float m11 = 0, m22 = 0, m12 = 0;
                #pragma unroll
                for (int dy = 0; dy < 11; dy++) {
                    float w = g[dy];
                    m11 += w * w0[p + dy];
                    m22 += w * w1[p + dy];
                    m12 += w * w2[p + dy];
                }
                float mu1s = mu1[p] * mu1[p], mu2s = mu2[p] * mu2[p];
                float mu12 = mu1[p] * mu2[p];
                float s1 = m11 - mu1s, s2 = m22 - mu2s, s12 = m12 - mu12;
                lsum += ((2.f * mu12 + C1) * (2.f * s12 + C2))
                      / ((mu1s + mu2s + C1) * (s1 + s2 + C2));
            }
        }
        #pragma unroll
        for (int off = 32; off; off >>= 1) lsum += __shfl_down(lsum, off, 64);
        if ((tid & 63) == 0) swred[tid >> 6][6] = lsum;
        __syncthreads();
        if (tid == 0)
            wsf[WS_SSIM + bid] = swred[0][6] + swred[1][6] + swred[2][6] + swred[3][6];
    } else {
        // -------- hist + depth chunk --------
        int c = bid - NTILE;
        int* lh = (int*)smem;
        for (int i = tid; i < K_FINE; i += NTHR) lh[i] = 0;
        __syncthreads();
        int batch = c / NHC, chunk = c % NHC;
        const float4* x4 = (const float4*)x  + (size_t)batch * (HW / 4) + chunk * 1536;
        const float4* d4 = (const float4*)dp + (size_t)batch * (HW / 4) + chunk * 1536;
        float dsum = 0.f;
        for (int i = tid; i < 1536; i += NTHR) {
            float4 xv = x4[i], dv = d4[i];
            float o0 = (xv.x - xmn) * xinv, o1 = (xv.y - xmn) * xinv;
            float o2 = (xv.z - xmn) * xinv, o3 = (xv.w - xmn) * xinv;
            dsum += o0 * ((dv.x - dmn) * dinv) + o1 * ((dv.y - dmn) * dinv)
                  + o2 * ((dv.z - dmn) * dinv) + o3 * ((dv.w - dmn) * dinv);
            int j0 = min(K_FINE - 1, max(0, (int)(o0 * K_FINE)));
            int j1 = min(K_FINE - 1, max(0, (int)(o1 * K_FINE)));
            int j2 = min(K_FINE - 1, max(0, (int)(o2 * K_FINE)));
            int j3 = min(K_FINE - 1, max(0, (int)(o3 * K_FINE)));
            atomicAdd(lh + j0, 1); atomicAdd(lh + j1, 1);
            atomicAdd(lh + j2, 1); atomicAdd(lh + j3, 1);
        }
        __syncthreads();
        int* gh = (int*)wsf + WS_HIST + batch * K_FINE;
        for (int i = tid; i < K_FINE; i += NTHR) {
            int v = lh[i];
            if (v) atomicAdd(gh + i, v);
        }
        #pragma unroll
        for (int off = 32; off; off >>= 1) dsum += __shfl_down(dsum, off, 64);
        if ((tid & 63) == 0) swred[tid >> 6][6] = dsum;
        __syncthreads();
        if (tid == 0)
            wsf[WS_DEPTH + c] = swred[0][6] + swred[1][6] + swred[2][6] + swred[3][6];
    }
}

// ================= K3: soft-hist entropy + last-block final combine =========
__global__ __launch_bounds__(NTHR) void k_soft_final(
        float* __restrict__ wsf, float* __restrict__ out)
{
    __shared__ int lh[K_FINE];
    __shared__ float s8[8];
    __shared__ int amLast;
    const int tid = threadIdx.x, bid = blockIdx.x;
    int batch = bid >> 5;
    const int* gh = (const int*)wsf + WS_HIST + batch * K_FINE;
    for (int i = tid; i < K_FINE; i += NTHR) lh[i] = gh[i];
    __syncthreads();
    int binLocal = tid >> 5, slice = tid & 31;
    int bin = (bid & 31) * 8 + binLocal;
    const float delta = 1.0f / 256.0f;
    const float r   = expf(3.0f * delta);
    const float rm1 = r - 1.0f;
    const float c32 = expf(-3.0f * 32.0f / (float)K_FINE);
    float L = (float)bin * delta;
    float u = expf(3.0f * (L - ((float)slice + 0.5f) * (1.0f / (float)K_FINE)));
    float h = 0.f;
    #pragma unroll 4
    for (int j = slice; j < K_FINE; j += 32) {
        float cnt = (float)lh[j];
        float t1 = 1.0f + u;
        float t2 = fmaf(u, r, 1.0f);
        h = fmaf(cnt * (u * rm1), __builtin_amdgcn_rcpf(t1 * t2), h);
        u *= c32;
    }
    #pragma unroll
    for (int off = 16; off; off >>= 1) h += __shfl_down(h, off, 32);
    if (slice == 0) s8[binLocal] = h;
    __syncthreads();
    if (tid == 0) {
        float hl = 0.f;
        #pragma unroll
        for (int b = 0; b < 8; b++) {
            float hh = s8[b];
            hl += (hh > 0.f) ? hh * logf(hh) : 0.f;
        }
        wsf[WS_UNIF + bid] = hl;
        __threadfence();
        int old = atomicAdd((int*)wsf + WS_TICKET, 1);
        amLast = (old == 255);
    }
    __syncthreads();
    if (amLast) {
        __threadfence();  // acquire: all partials visible
        float a = 0.f, bsum = 0.f, c = 0.f;
        for (int i = tid; i < NHIST; i += NTHR) a    += wsf[WS_DEPTH + i];
        for (int i = tid; i < NTILE; i += NTHR) bsum += wsf[WS_SSIM + i];
        for (int i = tid; i < 256;   i += NTHR) c    += wsf[WS_UNIF + i];
        float* ra = (float*)lh; float* rb = ra + 256; float* rc = rb + 256;
        ra[tid] = a; rb[tid] = bsum; rc[tid] = c;
        __syncthreads();
        for (int s = 128; s; s >>= 1) {
            if (tid < s) {
                ra[tid] += ra[tid + s];
                rb[tid] += rb[tid + s];
                rc[tid] += rc[tid + s];
            }
            __syncthreads();
        }
        if (tid == 0) {
            float uniform  = rc[0] / 8.0f;
            float depthL   = ra[0] / 8.0f;
            float ssimMean = rb[0] / (float)N1;
            out[0] = 1e-6f * uniform + 1e-5f * depthL + (1.0f - ssimMean);
        }
    }
}

extern "C" void kernel_launch(void* const* d_in, const int* in_sizes, int n_in,
                              void* d_out, int out_size, void* d_ws, size_t ws_size,
                              hipStream_t stream) {
    const float* x  = (const float*)d_in[0];
    const float* tg = (const float*)d_in[1];
    const float* dp = (const float*)d_in[2];
    float* wsf = (float*)d_ws;
    float* out = (float*)d_out;
    hipLaunchKernelGGL(k_minmax,     dim3(256),          dim3(NTHR), 0, stream, x, tg, dp, wsf);
    hipLaunchKernelGGL(k_work,       dim3(NTILE+NHIST),  dim3(NTHR), 0, stream, x, tg, dp, wsf);
    hipLaunchKernelGGL(k_soft_final, dim3(256),          dim3(NTHR), 0, stream, wsf, out);
}